// Round 3
// baseline (599.381 us; speedup 1.0000x reference)
//
#include <hip/hip_runtime.h>

// ---------------------------------------------------------------------------
// Qwen3 attention block: B=2 S=1024 H=4096 NH=32 NKV=8 D=128
// Round 3: XCD-aware L2-locality swizzles.
//  - GEMM: 1-D grid, N-strip pinned to XCD (id&7), M fastest within strip.
//    W-strip (1MB) stays L2-resident across 16 consecutive same-XCD blocks.
//  - attn: KV-group pinned to XCD (2 groups/XCD = 1MB K + 1MB V in 4MB L2).
// ---------------------------------------------------------------------------

typedef float  f32x4  __attribute__((ext_vector_type(4)));
typedef __bf16 bf16x8 __attribute__((ext_vector_type(8)));
typedef unsigned short u16x8 __attribute__((ext_vector_type(8)));

__device__ __forceinline__ unsigned short f2b(float f) {
    union { float f; unsigned int u; } x;
    x.f = f;
    unsigned int u = x.u;
    unsigned int r = u + 0x7fffu + ((u >> 16) & 1u);   // RNE
    return (unsigned short)(r >> 16);
}

// async global->LDS, 16B per lane. LDS dst = wave-uniform base + lane*16.
__device__ __forceinline__ void async16(const unsigned short* g, unsigned short* l) {
    __builtin_amdgcn_global_load_lds(
        (const __attribute__((address_space(1))) void*)g,
        (__attribute__((address_space(3))) void*)l, 16, 0, 0);
}

// ---------------------------------------------------------------------------
// fp32 -> bf16 convert, 8 elems/thread
// ---------------------------------------------------------------------------
__global__ __launch_bounds__(256) void cvt(const float* __restrict__ s,
                                           unsigned short* __restrict__ d, int n8) {
    int i = blockIdx.x * 256 + threadIdx.x;
    if (i >= n8) return;
    const float4* s4 = (const float4*)s + (size_t)i * 2;
    float4 a = s4[0], b = s4[1];
    u16x8 o;
    o[0] = f2b(a.x); o[1] = f2b(a.y); o[2] = f2b(a.z); o[3] = f2b(a.w);
    o[4] = f2b(b.x); o[5] = f2b(b.y); o[6] = f2b(b.z); o[7] = f2b(b.w);
    *((u16x8*)d + i) = o;
}

// ---------------------------------------------------------------------------
// GEMM: C[M,N] fp32 = A[M,K]bf16 @ W[N,K]bf16^T. 128x128 tile, BK=64.
// M is fixed at 2048 (16 M-blocks). 1-D grid = 16 * NB, NB = 8*NB8 N-blocks.
// Block id -> (m, n): xcd = id&7, t = id>>3, m = t&15, n = xcd*NB8 + (t>>4).
// global_load_lds(16B) staging with XOR-8 chunk swizzle (conflict-free frags).
// ---------------------------------------------------------------------------
__global__ __launch_bounds__(256) void gemm_bt_bf16(const unsigned short* __restrict__ A,
                                                    const unsigned short* __restrict__ W,
                                                    float* __restrict__ C,
                                                    int K, int N, int NB8) {
    __shared__ __align__(16) unsigned short As[128 * 64];
    __shared__ __align__(16) unsigned short Bs[128 * 64];

    const int tid  = threadIdx.x;
    const int wave = tid >> 6, lane = tid & 63;
    const int wm   = wave >> 1, wn = wave & 1;
    const int quad = lane >> 4, l15 = lane & 15;

    const int id  = blockIdx.x;
    const int xcd = id & 7;
    const int t   = id >> 3;
    const int mb  = t & 15;
    const int nb  = xcd * NB8 + (t >> 4);
    const int arow = mb * 128, brow = nb * 128;

    // per-thread staging coordinates (chunk-linear over the 128x8-chunk tile)
    int rr[4], gc[4], slot[4];
    #pragma unroll
    for (int it = 0; it < 4; it++) {
        slot[it] = it * 4 + wave;
        int ci = slot[it] * 64 + lane;
        rr[it] = ci >> 3;
        int c  = ci & 7;
        gc[it] = c ^ (rr[it] & 7);
    }

    f32x4 acc[4][4] = {};

    for (int k0 = 0; k0 < K; k0 += 64) {
        #pragma unroll
        for (int it = 0; it < 4; it++) {
            async16(A + (size_t)(arow + rr[it]) * K + k0 + gc[it] * 8, &As[slot[it] * 512]);
            async16(W + (size_t)(brow + rr[it]) * K + k0 + gc[it] * 8, &Bs[slot[it] * 512]);
        }
        __syncthreads();

        bf16x8 af[2][4], bfr[2][4];
        #pragma unroll
        for (int ks = 0; ks < 2; ks++) {
            #pragma unroll
            for (int i = 0; i < 4; i++) {
                int rowa = wm * 64 + i * 16 + l15;
                int ch   = (ks * 4 + quad) ^ (l15 & 7);
                af[ks][i]  = *(const bf16x8*)&As[rowa * 64 + ch * 8];
                int rowb = wn * 64 + i * 16 + l15;
                bfr[ks][i] = *(const bf16x8*)&Bs[rowb * 64 + ch * 8];
            }
        }
        #pragma unroll
        for (int ks = 0; ks < 2; ks++)
            #pragma unroll
            for (int i = 0; i < 4; i++)
                #pragma unroll
                for (int j = 0; j < 4; j++)
                    acc[i][j] = __builtin_amdgcn_mfma_f32_16x16x32_bf16(af[ks][i], bfr[ks][j], acc[i][j], 0, 0, 0);
        __syncthreads();
    }

    #pragma unroll
    for (int i = 0; i < 4; i++)
        #pragma unroll
        for (int j = 0; j < 4; j++)
            #pragma unroll
            for (int r = 0; r < 4; r++) {
                int row = arow + wm * 64 + i * 16 + quad * 4 + r;
                int col = brow + wn * 64 + j * 16 + l15;
                C[(size_t)row * N + col] = acc[i][j][r];
            }
}

// ---------------------------------------------------------------------------
// RMSNorm + RoPE: fp32 [rows][rstride] (col-offset pre-applied) -> bf16
// [B][nh][S][128]. One wave per (row, head).
// ---------------------------------------------------------------------------
__global__ __launch_bounds__(256) void norm_rope(const float* __restrict__ X, int rstride,
                                                 const float* __restrict__ cosp,
                                                 const float* __restrict__ sinp,
                                                 const float* __restrict__ w,
                                                 unsigned short* __restrict__ Y, int nh) {
    const int wid  = blockIdx.x * 4 + (threadIdx.x >> 6);
    const int lane = threadIdx.x & 63;
    const int row  = wid / nh;
    const int h    = wid - row * nh;

    const float* xp = X + (size_t)row * rstride + h * 128;
    float x0 = xp[lane], x1 = xp[lane + 64];
    float ss = x0 * x0 + x1 * x1;
    #pragma unroll
    for (int off = 32; off; off >>= 1) ss += __shfl_xor(ss, off, 64);
    float r = rsqrtf(ss * (1.0f / 128.0f) + 1e-6f);
    float n0 = x0 * r * w[lane];
    float n1 = x1 * r * w[lane + 64];
    const float* cp = cosp + (size_t)row * 128;
    const float* sp = sinp + (size_t)row * 128;
    float y0 = n0 * cp[lane]      - n1 * sp[lane];
    float y1 = n1 * cp[lane + 64] + n0 * sp[lane + 64];
    const int b = row >> 10, s = row & 1023;
    unsigned short* yp = Y + (((size_t)(b * nh + h)) * 1024 + s) * 128;
    yp[lane]      = f2b(y0);
    yp[lane + 64] = f2b(y1);
}

// ---------------------------------------------------------------------------
// V transpose via LDS: fp32 V-region rows [b*1024+s][6144] (pointer
// pre-offset to col 5120) -> bf16 Vt[b][h][128][1024]. 64x64 tiles.
// ---------------------------------------------------------------------------
__global__ __launch_bounds__(256) void v_trans(const float* __restrict__ V,
                                               unsigned short* __restrict__ Vt) {
    __shared__ float T[64][65];
    const int tid = threadIdx.x;
    const int st = blockIdx.x >> 1, dt = blockIdx.x & 1;
    const int bh = blockIdx.y, b = bh >> 3, h = bh & 7;

    const int sl = tid >> 2, c0 = (tid & 3) * 16;
    const float* src = V + (size_t)(b * 1024 + st * 64 + sl) * 6144 + h * 128 + dt * 64 + c0;
    #pragma unroll
    for (int j = 0; j < 4; j++) {
        float4 v = *(const float4*)(src + j * 4);
        *(float4*)&T[sl][c0 + j * 4] = v;
    }
    __syncthreads();

    const int dgrp = tid >> 6, sl2 = tid & 63;
    unsigned short* dst = Vt + (size_t)bh * 131072 + st * 64 + sl2;
    #pragma unroll
    for (int jd = 0; jd < 16; jd++) {
        int dl = dgrp * 16 + jd;
        dst[(size_t)(dt * 64 + dl) * 1024] = f2b(T[sl2][dl]);
    }
}

// ---------------------------------------------------------------------------
// Flash attention (causal, GQA 4:1). 1-D grid of 512 blocks:
//   g = id & 15 (KV group: b = g>>3, kvh = g&7) -> XCD = id%8 = g%8, so each
//   XCD serves 2 KV groups (1MB K + 1MB V, L2-resident).
//   s = id >> 4 in [0,32): h = kvh*4 + (s&3), qt_base = s>>2.
// Block = 64 Q rows (4 waves x 16), q-tiles {qt, 15-qt} -> 9 k-tiles/block.
// K staged in LDS (swizzled async16), exp2 softmax, mask only diagonal tile.
// ---------------------------------------------------------------------------
__global__ __launch_bounds__(256) void attn(const unsigned short* __restrict__ Qb,
                                            const unsigned short* __restrict__ Kb,
                                            const unsigned short* __restrict__ Vt,
                                            unsigned short* __restrict__ Ob) {
    __shared__ __align__(16) unsigned short Klds[128 * 128];
    __shared__ __align__(16) unsigned short Plds[4][16][136];

    const int tid  = threadIdx.x;
    const int w    = tid >> 6, lane = tid & 63;
    const int quad = lane >> 4, l15 = lane & 15;

    const int id = blockIdx.x;
    const int g  = id & 15, s = id >> 4;
    const int b  = g >> 3, kvh = g & 7;
    const int h  = kvh * 4 + (s & 3);
    const int qt_base = s >> 2;

    const unsigned short* Qp = Qb + ((size_t)(b * 32 + h))  * 131072;
    const unsigned short* Kp = Kb + ((size_t)(b * 8 + kvh)) * 131072;
    const unsigned short* Vp = Vt + ((size_t)(b * 8 + kvh)) * 131072;
    const float c2 = (float)(0.08838834764831845 * 1.4426950408889634); // D^-.5 * log2(e)

    for (int half = 0; half < 2; half++) {
        const int qt = half ? (15 - qt_base) : qt_base;
        const int q0 = qt * 64;
        const int qrow = q0 + w * 16 + l15;

        bf16x8 qf[4];
        #pragma unroll
        for (int ks = 0; ks < 4; ks++)
            qf[ks] = *(const bf16x8*)(Qp + (size_t)qrow * 128 + ks * 32 + quad * 8);

        float m_i[4], l_i[4];
        #pragma unroll
        for (int r = 0; r < 4; r++) { m_i[r] = -1e30f; l_i[r] = 0.0f; }
        f32x4 o[8] = {};

        const int ntiles = (qt >> 1) + 1;
        const int nfull  = (qt * 64 + 1) >> 7;   // tiles [0,nfull) need no mask

        for (int kt = 0; kt < ntiles; kt++) {
            __syncthreads();   // Klds readers of previous tile are done
            #pragma unroll
            for (int it = 0; it < 8; it++) {
                int slot = it * 4 + w;
                int ci = slot * 64 + lane;
                int r = ci >> 4, c = ci & 15;
                int gch = (c & 8) | ((c ^ r) & 7);
                async16(Kp + (size_t)(kt * 128 + r) * 128 + gch * 8, &Klds[slot * 512]);
            }
            __syncthreads();

            // S = Q @ K^T
            f32x4 sacc[8] = {};
            #pragma unroll
            for (int ks = 0; ks < 4; ks++) {
                #pragma unroll
                for (int tn = 0; tn < 8; tn++) {
                    int row = tn * 16 + l15;
                    int ch  = ks * 4 + quad;
                    int chs = (ch & 8) | ((ch ^ row) & 7);
                    bf16x8 kf = *(const bf16x8*)&Klds[row * 128 + chs * 8];
                    sacc[tn] = __builtin_amdgcn_mfma_f32_16x16x32_bf16(qf[ks], kf, sacc[tn], 0, 0, 0);
                }
            }

            const bool masked = (kt >= nfull);
            #pragma unroll
            for (int r = 0; r < 4; r++) {
                float sv[8];
                float rmax = -1e30f;
                if (masked) {
                    const int qg = q0 + w * 16 + quad * 4 + r;
                    #pragma unroll
                    for (int tn = 0; tn < 8; tn++) {
                        float v = sacc[tn][r];
                        int kg = kt * 128 + tn * 16 + l15;
                        if (kg > qg) v = -1e30f;
                        sv[tn] = v;
                        rmax = fmaxf(rmax, v);
                    }
                } else {
                    #pragma unroll
                    for (int tn = 0; tn < 8; tn++) {
                        sv[tn] = sacc[tn][r];
                        rmax = fmaxf(rmax, sv[tn]);
                    }
                }
                #pragma unroll
                for (int off = 8; off; off >>= 1) rmax = fmaxf(rmax, __shfl_xor(rmax, off, 16));
                float mnew  = fmaxf(m_i[r], rmax);
                float alpha = __builtin_amdgcn_exp2f((m_i[r] - mnew) * c2);
                float rsum  = 0.0f;
                #pragma unroll
                for (int tn = 0; tn < 8; tn++) {
                    float p = __builtin_amdgcn_exp2f((sv[tn] - mnew) * c2);
                    sv[tn] = p;
                    rsum += p;
                }
                #pragma unroll
                for (int off = 8; off; off >>= 1) rsum += __shfl_xor(rsum, off, 16);
                m_i[r] = mnew;
                l_i[r] = l_i[r] * alpha + rsum;
                #pragma unroll
                for (int td = 0; td < 8; td++) o[td][r] *= alpha;
                #pragma unroll
                for (int tn = 0; tn < 8; tn++)
                    Plds[w][quad * 4 + r][tn * 16 + l15] = f2b(sv[tn]);
            }

            // O += P @ V
            #pragma unroll
            for (int ks = 0; ks < 4; ks++) {
                bf16x8 pf = *(const bf16x8*)&Plds[w][l15][ks * 32 + quad * 8];
                #pragma unroll
                for (int td = 0; td < 8; td++) {
                    bf16x8 vf = *(const bf16x8*)(Vp + (size_t)(td * 16 + l15) * 1024 + kt * 128 + ks * 32 + quad * 8);
                    o[td] = __builtin_amdgcn_mfma_f32_16x16x32_bf16(pf, vf, o[td], 0, 0, 0);
                }
            }
        }

        #pragma unroll
        for (int r = 0; r < 4; r++) {
            float inv = 1.0f / l_i[r];
            const int qg = q0 + w * 16 + quad * 4 + r;
            unsigned short* op = Ob + ((size_t)(b * 1024 + qg)) * 4096 + h * 128;
            #pragma unroll
            for (int td = 0; td < 8; td++)
                op[td * 16 + l15] = f2b(o[td][r] * inv);
        }
    }
}

// ---------------------------------------------------------------------------
extern "C" void kernel_launch(void* const* d_in, const int* in_sizes, int n_in,
                              void* d_out, int out_size, void* d_ws, size_t ws_size,
                              hipStream_t stream) {
    const float* hid  = (const float*)d_in[0];
    const float* cosp = (const float*)d_in[1];
    const float* sinp = (const float*)d_in[2];
    const float* Wq   = (const float*)d_in[3];
    const float* Wk   = (const float*)d_in[4];
    const float* Wv   = (const float*)d_in[5];
    const float* Wo   = (const float*)d_in[6];
    const float* qw   = (const float*)d_in[7];
    const float* kw   = (const float*)d_in[8];
    float* out = (float*)d_out;

    // workspace carve (~176 MB)
    char* ws = (char*)d_ws;
    float* QKVf = (float*)ws;                               // [2048][6144] fp32 (50.3MB)
    unsigned short* Ob = (unsigned short*)ws;               // alias: QKVf dead before attn
    size_t off = (size_t)2048 * 6144 * 4;
    unsigned short* hidb  = (unsigned short*)(ws + off); off += (size_t)2048 * 4096 * 2;
    unsigned short* Wqkvb = (unsigned short*)(ws + off); off += (size_t)6144 * 4096 * 2;
    unsigned short* Wob   = (unsigned short*)(ws + off); off += (size_t)4096 * 4096 * 2;
    unsigned short* Qb    = (unsigned short*)(ws + off); off += (size_t)2048 * 4096 * 2;
    unsigned short* Kb    = (unsigned short*)(ws + off); off += (size_t)2048 * 1024 * 2;
    unsigned short* Vt    = (unsigned short*)(ws + off);

    dim3 blk(256);
    // fp32 -> bf16 converts
    cvt<<<4096, blk, 0, stream>>>(hid, hidb, 1048576);
    cvt<<<8192, blk, 0, stream>>>(Wq, Wqkvb, 2097152);
    cvt<<<2048, blk, 0, stream>>>(Wk, Wqkvb + (size_t)4096 * 4096, 524288);
    cvt<<<2048, blk, 0, stream>>>(Wv, Wqkvb + (size_t)5120 * 4096, 524288);
    cvt<<<8192, blk, 0, stream>>>(Wo, Wob, 2097152);
    // fused QKV projection: [2048][6144] = hidb @ Wqkvb^T  (48 N-blocks, 6/XCD)
    gemm_bt_bf16<<<768, blk, 0, stream>>>(hidb, Wqkvb, QKVf, 4096, 6144, 6);
    // norm + rope + layout
    norm_rope<<<16384, blk, 0, stream>>>(QKVf,        6144, cosp, sinp, qw, Qb, 32);
    norm_rope<<<4096,  blk, 0, stream>>>(QKVf + 4096, 6144, cosp, sinp, kw, Kb, 8);
    v_trans<<<dim3(32, 16), blk, 0, stream>>>(QKVf + 5120, Vt);
    // attention (KV-group XCD-pinned)
    attn<<<512, blk, 0, stream>>>(Qb, Kb, Vt, Ob);
    // output projection (32 N-blocks, 4/XCD)
    gemm_bt_bf16<<<512, blk, 0, stream>>>(Ob, Wob, out, 4096, 4096, 4);
}

// Round 4
// 511.076 us; speedup vs baseline: 1.1728x; 1.1728x over previous
//
#include <hip/hip_runtime.h>

// ---------------------------------------------------------------------------
// Qwen3 attention block: B=2 S=1024 H=4096 NH=32 NKV=8 D=128
// Round 4: revert round-3 XCD swizzle (regressed: FETCH 119->156MB — block->XCD
// mapping is NOT id%8; grid back to round-2 2-D). GEMM inner loop switched to
// v_mfma_f32_32x32x16_bf16 (2382 vs 2075 TF ubench; ~128 vs ~155 mfma-cyc per
// BK=64 iter at identical LDS traffic).
// ---------------------------------------------------------------------------

typedef float  f32x4   __attribute__((ext_vector_type(4)));
typedef float  f32x16  __attribute__((ext_vector_type(16)));
typedef __bf16 bf16x8  __attribute__((ext_vector_type(8)));
typedef unsigned short u16x8 __attribute__((ext_vector_type(8)));

__device__ __forceinline__ unsigned short f2b(float f) {
    union { float f; unsigned int u; } x;
    x.f = f;
    unsigned int u = x.u;
    unsigned int r = u + 0x7fffu + ((u >> 16) & 1u);   // RNE
    return (unsigned short)(r >> 16);
}

// async global->LDS, 16B per lane. LDS dst = wave-uniform base + lane*16.
__device__ __forceinline__ void async16(const unsigned short* g, unsigned short* l) {
    __builtin_amdgcn_global_load_lds(
        (const __attribute__((address_space(1))) void*)g,
        (__attribute__((address_space(3))) void*)l, 16, 0, 0);
}

// ---------------------------------------------------------------------------
// fp32 -> bf16 convert, 8 elems/thread
// ---------------------------------------------------------------------------
__global__ __launch_bounds__(256) void cvt(const float* __restrict__ s,
                                           unsigned short* __restrict__ d, int n8) {
    int i = blockIdx.x * 256 + threadIdx.x;
    if (i >= n8) return;
    const float4* s4 = (const float4*)s + (size_t)i * 2;
    float4 a = s4[0], b = s4[1];
    u16x8 o;
    o[0] = f2b(a.x); o[1] = f2b(a.y); o[2] = f2b(a.z); o[3] = f2b(a.w);
    o[4] = f2b(b.x); o[5] = f2b(b.y); o[6] = f2b(b.z); o[7] = f2b(b.w);
    *((u16x8*)d + i) = o;
}

// ---------------------------------------------------------------------------
// GEMM: C[M,N] fp32 = A[M,K]bf16 @ W[N,K]bf16^T. 128x128 tile, BK=64.
// 4 waves 2x2; each wave 64x64 via 2x2 grid of mfma_f32_32x32x16_bf16.
// A-frag: lane holds A[m=l&31][k=(l>>5)*8+j]   (j=0..7)
// B-frag: lane holds W[n=l&31][k=(l>>5)*8+j]
// C/D:    lane holds D[row=(r&3)+8*(r>>2)+4*(l>>5)][col=l&31], r=0..15
// Staging: global_load_lds(16B) with XOR-8 chunk swizzle
//   LDS[row][c] = global chunk (c ^ (row&7));  frag read col = g ^ (row&7).
// ---------------------------------------------------------------------------
__global__ __launch_bounds__(256) void gemm_bt_bf16(const unsigned short* __restrict__ A,
                                                    const unsigned short* __restrict__ W,
                                                    float* __restrict__ C,
                                                    int K, int N) {
    __shared__ __align__(16) unsigned short As[128 * 64];
    __shared__ __align__(16) unsigned short Bs[128 * 64];

    const int tid  = threadIdx.x;
    const int wave = tid >> 6, lane = tid & 63;
    const int wm   = wave >> 1, wn = wave & 1;
    const int l31  = lane & 31, lh = lane >> 5;
    const int arow = blockIdx.y * 128, brow = blockIdx.x * 128;

    // per-thread staging coordinates (chunk-linear over the 128x8-chunk tile)
    int rr[4], gc[4], slot[4];
    #pragma unroll
    for (int it = 0; it < 4; it++) {
        slot[it] = it * 4 + wave;
        int ci = slot[it] * 64 + lane;
        rr[it] = ci >> 3;
        int c  = ci & 7;
        gc[it] = c ^ (rr[it] & 7);
    }

    f32x16 acc[2][2] = {};

    for (int k0 = 0; k0 < K; k0 += 64) {
        #pragma unroll
        for (int it = 0; it < 4; it++) {
            async16(A + (size_t)(arow + rr[it]) * K + k0 + gc[it] * 8, &As[slot[it] * 512]);
            async16(W + (size_t)(brow + rr[it]) * K + k0 + gc[it] * 8, &Bs[slot[it] * 512]);
        }
        __syncthreads();

        bf16x8 af[4][2], bfr[4][2];
        #pragma unroll
        for (int ks = 0; ks < 4; ks++) {
            #pragma unroll
            for (int i = 0; i < 2; i++) {
                int rowa = wm * 64 + i * 32 + l31;
                int ch   = (ks * 2 + lh) ^ (rowa & 7);
                af[ks][i]  = *(const bf16x8*)&As[rowa * 64 + ch * 8];
                int rowb = wn * 64 + i * 32 + l31;
                int chb  = (ks * 2 + lh) ^ (rowb & 7);
                bfr[ks][i] = *(const bf16x8*)&Bs[rowb * 64 + chb * 8];
            }
        }
        #pragma unroll
        for (int ks = 0; ks < 4; ks++)
            #pragma unroll
            for (int i = 0; i < 2; i++)
                #pragma unroll
                for (int j = 0; j < 2; j++)
                    acc[i][j] = __builtin_amdgcn_mfma_f32_32x32x16_bf16(af[ks][i], bfr[ks][j], acc[i][j], 0, 0, 0);
        __syncthreads();
    }

    #pragma unroll
    for (int i = 0; i < 2; i++)
        #pragma unroll
        for (int j = 0; j < 2; j++)
            #pragma unroll
            for (int r = 0; r < 16; r++) {
                int row = arow + wm * 64 + i * 32 + lh * 4 + (r & 3) + 8 * (r >> 2);
                int col = brow + wn * 64 + j * 32 + l31;
                C[(size_t)row * N + col] = acc[i][j][r];
            }
}

// ---------------------------------------------------------------------------
// RMSNorm + RoPE: fp32 [rows][rstride] (col-offset pre-applied) -> bf16
// [B][nh][S][128]. One wave per (row, head).
// ---------------------------------------------------------------------------
__global__ __launch_bounds__(256) void norm_rope(const float* __restrict__ X, int rstride,
                                                 const float* __restrict__ cosp,
                                                 const float* __restrict__ sinp,
                                                 const float* __restrict__ w,
                                                 unsigned short* __restrict__ Y, int nh) {
    const int wid  = blockIdx.x * 4 + (threadIdx.x >> 6);
    const int lane = threadIdx.x & 63;
    const int row  = wid / nh;
    const int h    = wid - row * nh;

    const float* xp = X + (size_t)row * rstride + h * 128;
    float x0 = xp[lane], x1 = xp[lane + 64];
    float ss = x0 * x0 + x1 * x1;
    #pragma unroll
    for (int off = 32; off; off >>= 1) ss += __shfl_xor(ss, off, 64);
    float r = rsqrtf(ss * (1.0f / 128.0f) + 1e-6f);
    float n0 = x0 * r * w[lane];
    float n1 = x1 * r * w[lane + 64];
    const float* cp = cosp + (size_t)row * 128;
    const float* sp = sinp + (size_t)row * 128;
    float y0 = n0 * cp[lane]      - n1 * sp[lane];
    float y1 = n1 * cp[lane + 64] + n0 * sp[lane + 64];
    const int b = row >> 10, s = row & 1023;
    unsigned short* yp = Y + (((size_t)(b * nh + h)) * 1024 + s) * 128;
    yp[lane]      = f2b(y0);
    yp[lane + 64] = f2b(y1);
}

// ---------------------------------------------------------------------------
// V transpose via LDS: fp32 V-region rows [b*1024+s][6144] (pointer
// pre-offset to col 5120) -> bf16 Vt[b][h][128][1024]. 64x64 tiles.
// ---------------------------------------------------------------------------
__global__ __launch_bounds__(256) void v_trans(const float* __restrict__ V,
                                               unsigned short* __restrict__ Vt) {
    __shared__ float T[64][65];
    const int tid = threadIdx.x;
    const int st = blockIdx.x >> 1, dt = blockIdx.x & 1;
    const int bh = blockIdx.y, b = bh >> 3, h = bh & 7;

    const int sl = tid >> 2, c0 = (tid & 3) * 16;
    const float* src = V + (size_t)(b * 1024 + st * 64 + sl) * 6144 + h * 128 + dt * 64 + c0;
    #pragma unroll
    for (int j = 0; j < 4; j++) {
        float4 v = *(const float4*)(src + j * 4);
        *(float4*)&T[sl][c0 + j * 4] = v;
    }
    __syncthreads();

    const int dgrp = tid >> 6, sl2 = tid & 63;
    unsigned short* dst = Vt + (size_t)bh * 131072 + st * 64 + sl2;
    #pragma unroll
    for (int jd = 0; jd < 16; jd++) {
        int dl = dgrp * 16 + jd;
        dst[(size_t)(dt * 64 + dl) * 1024] = f2b(T[sl2][dl]);
    }
}

// ---------------------------------------------------------------------------
// Flash attention (causal, GQA 4:1). Block = 64 Q rows (4 waves x 16 rows),
// processes q-tiles {qt, 15-qt} -> 9 k-tiles per block (balanced).
// K-tile (128x128) staged in LDS via swizzled global_load_lds, shared by all
// waves. Softmax in exp2 domain; mask only on the single diagonal tile.
// Output bf16 [b*1024+q][4096].
// ---------------------------------------------------------------------------
__global__ __launch_bounds__(256) void attn(const unsigned short* __restrict__ Qb,
                                            const unsigned short* __restrict__ Kb,
                                            const unsigned short* __restrict__ Vt,
                                            unsigned short* __restrict__ Ob) {
    __shared__ __align__(16) unsigned short Klds[128 * 128];
    __shared__ __align__(16) unsigned short Plds[4][16][136];

    const int tid  = threadIdx.x;
    const int w    = tid >> 6, lane = tid & 63;
    const int quad = lane >> 4, l15 = lane & 15;
    const int h = blockIdx.y, b = blockIdx.z, kvh = h >> 2;

    const unsigned short* Qp = Qb + ((size_t)(b * 32 + h))   * 131072;
    const unsigned short* Kp = Kb + ((size_t)(b * 8 + kvh))  * 131072;
    const unsigned short* Vp = Vt + ((size_t)(b * 8 + kvh))  * 131072;
    const float c2 = (float)(0.08838834764831845 * 1.4426950408889634); // D^-.5 * log2(e)

    for (int half = 0; half < 2; half++) {
        const int qt = half ? (15 - (int)blockIdx.x) : (int)blockIdx.x;
        const int q0 = qt * 64;
        const int qrow = q0 + w * 16 + l15;

        bf16x8 qf[4];
        #pragma unroll
        for (int ks = 0; ks < 4; ks++)
            qf[ks] = *(const bf16x8*)(Qp + (size_t)qrow * 128 + ks * 32 + quad * 8);

        float m_i[4], l_i[4];
        #pragma unroll
        for (int r = 0; r < 4; r++) { m_i[r] = -1e30f; l_i[r] = 0.0f; }
        f32x4 o[8] = {};

        const int ntiles = (qt >> 1) + 1;
        const int nfull  = (qt * 64 + 1) >> 7;   // tiles [0,nfull) need no mask

        for (int kt = 0; kt < ntiles; kt++) {
            __syncthreads();   // Klds readers of previous tile are done
            #pragma unroll
            for (int it = 0; it < 8; it++) {
                int slot = it * 4 + w;
                int ci = slot * 64 + lane;
                int r = ci >> 4, c = ci & 15;
                int g = (c & 8) | ((c ^ r) & 7);
                async16(Kp + (size_t)(kt * 128 + r) * 128 + g * 8, &Klds[slot * 512]);
            }
            __syncthreads();

            // S = Q @ K^T
            f32x4 sacc[8] = {};
            #pragma unroll
            for (int ks = 0; ks < 4; ks++) {
                #pragma unroll
                for (int tn = 0; tn < 8; tn++) {
                    int row = tn * 16 + l15;
                    int ch  = ks * 4 + quad;
                    int chs = (ch & 8) | ((ch ^ row) & 7);
                    bf16x8 kf = *(const bf16x8*)&Klds[row * 128 + chs * 8];
                    sacc[tn] = __builtin_amdgcn_mfma_f32_16x16x32_bf16(qf[ks], kf, sacc[tn], 0, 0, 0);
                }
            }

            const bool masked = (kt >= nfull);
            #pragma unroll
            for (int r = 0; r < 4; r++) {
                float sv[8];
                float rmax = -1e30f;
                if (masked) {
                    const int qg = q0 + w * 16 + quad * 4 + r;
                    #pragma unroll
                    for (int tn = 0; tn < 8; tn++) {
                        float v = sacc[tn][r];
                        int kg = kt * 128 + tn * 16 + l15;
                        if (kg > qg) v = -1e30f;
                        sv[tn] = v;
                        rmax = fmaxf(rmax, v);
                    }
                } else {
                    #pragma unroll
                    for (int tn = 0; tn < 8; tn++) {
                        sv[tn] = sacc[tn][r];
                        rmax = fmaxf(rmax, sv[tn]);
                    }
                }
                #pragma unroll
                for (int off = 8; off; off >>= 1) rmax = fmaxf(rmax, __shfl_xor(rmax, off, 16));
                float mnew  = fmaxf(m_i[r], rmax);
                float alpha = __builtin_amdgcn_exp2f((m_i[r] - mnew) * c2);
                float rsum  = 0.0f;
                #pragma unroll
                for (int tn = 0; tn < 8; tn++) {
                    float p = __builtin_amdgcn_exp2f((sv[tn] - mnew) * c2);
                    sv[tn] = p;
                    rsum += p;
                }
                #pragma unroll
                for (int off = 8; off; off >>= 1) rsum += __shfl_xor(rsum, off, 16);
                m_i[r] = mnew;
                l_i[r] = l_i[r] * alpha + rsum;
                #pragma unroll
                for (int td = 0; td < 8; td++) o[td][r] *= alpha;
                #pragma unroll
                for (int tn = 0; tn < 8; tn++)
                    Plds[w][quad * 4 + r][tn * 16 + l15] = f2b(sv[tn]);
            }

            // O += P @ V
            #pragma unroll
            for (int ks = 0; ks < 4; ks++) {
                bf16x8 pf = *(const bf16x8*)&Plds[w][l15][ks * 32 + quad * 8];
                #pragma unroll
                for (int td = 0; td < 8; td++) {
                    bf16x8 vf = *(const bf16x8*)(Vp + (size_t)(td * 16 + l15) * 1024 + kt * 128 + ks * 32 + quad * 8);
                    o[td] = __builtin_amdgcn_mfma_f32_16x16x32_bf16(pf, vf, o[td], 0, 0, 0);
                }
            }
        }

        #pragma unroll
        for (int r = 0; r < 4; r++) {
            float inv = 1.0f / l_i[r];
            const int qg = q0 + w * 16 + quad * 4 + r;
            unsigned short* op = Ob + ((size_t)(b * 1024 + qg)) * 4096 + h * 128;
            #pragma unroll
            for (int td = 0; td < 8; td++)
                op[td * 16 + l15] = f2b(o[td][r] * inv);
        }
    }
}

// ---------------------------------------------------------------------------
extern "C" void kernel_launch(void* const* d_in, const int* in_sizes, int n_in,
                              void* d_out, int out_size, void* d_ws, size_t ws_size,
                              hipStream_t stream) {
    const float* hid  = (const float*)d_in[0];
    const float* cosp = (const float*)d_in[1];
    const float* sinp = (const float*)d_in[2];
    const float* Wq   = (const float*)d_in[3];
    const float* Wk   = (const float*)d_in[4];
    const float* Wv   = (const float*)d_in[5];
    const float* Wo   = (const float*)d_in[6];
    const float* qw   = (const float*)d_in[7];
    const float* kw   = (const float*)d_in[8];
    float* out = (float*)d_out;

    // workspace carve (~176 MB)
    char* ws = (char*)d_ws;
    float* QKVf = (float*)ws;                               // [2048][6144] fp32 (50.3MB)
    unsigned short* Ob = (unsigned short*)ws;               // alias: QKVf dead before attn
    size_t off = (size_t)2048 * 6144 * 4;
    unsigned short* hidb  = (unsigned short*)(ws + off); off += (size_t)2048 * 4096 * 2;
    unsigned short* Wqkvb = (unsigned short*)(ws + off); off += (size_t)6144 * 4096 * 2;
    unsigned short* Wob   = (unsigned short*)(ws + off); off += (size_t)4096 * 4096 * 2;
    unsigned short* Qb    = (unsigned short*)(ws + off); off += (size_t)2048 * 4096 * 2;
    unsigned short* Kb    = (unsigned short*)(ws + off); off += (size_t)2048 * 1024 * 2;
    unsigned short* Vt    = (unsigned short*)(ws + off);

    dim3 blk(256);
    // fp32 -> bf16 converts
    cvt<<<4096, blk, 0, stream>>>(hid, hidb, 1048576);
    cvt<<<8192, blk, 0, stream>>>(Wq, Wqkvb, 2097152);
    cvt<<<2048, blk, 0, stream>>>(Wk, Wqkvb + (size_t)4096 * 4096, 524288);
    cvt<<<2048, blk, 0, stream>>>(Wv, Wqkvb + (size_t)5120 * 4096, 524288);
    cvt<<<8192, blk, 0, stream>>>(Wo, Wob, 2097152);
    // fused QKV projection: [2048][6144] = hidb @ Wqkvb^T
    gemm_bt_bf16<<<dim3(48, 16), blk, 0, stream>>>(hidb, Wqkvb, QKVf, 4096, 6144);
    // norm + rope + layout
    norm_rope<<<16384, blk, 0, stream>>>(QKVf,        6144, cosp, sinp, qw, Qb, 32);
    norm_rope<<<4096,  blk, 0, stream>>>(QKVf + 4096, 6144, cosp, sinp, kw, Kb, 8);
    v_trans<<<dim3(32, 16), blk, 0, stream>>>(QKVf + 5120, Vt);
    // attention
    attn<<<dim3(8, 32, 2), blk, 0, stream>>>(Qb, Kb, Vt, Ob);
    // output projection
    gemm_bt_bf16<<<dim3(32, 16), blk, 0, stream>>>(Ob, Wob, out, 4096, 4096);
}